// Round 1
// baseline (6904.384 us; speedup 1.0000x reference)
//
#include <hip/hip_runtime.h>
#include <cmath>

#define B_ 256
#define T_ 20
#define H_ 512
#define V_ 8964
#define LQ_ 40
#define LH_ 80
#define LI_ 49
#define BT_ (B_ * T_)   // 5120
#define BETA_ 3.0f

// ---------------------------------------------------------------------------
// Generic fp32 GEMM:  C[m,n] = act( A1[m,:]·W1[n,:] + A2[m,:]·W2[n,:]
//                                   + bias1[n] + bias2[n] + D[m*ldd+n] )
// A row-major [M,K], W row-major [N,K]. M % 64 == 0, K % 16 == 0 guaranteed by
// caller; N guarded (V=8964). ACT: 0 none, 1 tanh, 2 relu.
// ---------------------------------------------------------------------------
template <int ACT>
__global__ __launch_bounds__(256) void gemm_kernel(
    const float* __restrict__ A1, const float* __restrict__ W1, int K1,
    const float* __restrict__ A2, const float* __restrict__ W2, int K2,
    const float* __restrict__ bias1, const float* __restrict__ bias2,
    const float* __restrict__ Dadd, long long ldd,
    float* __restrict__ C, long long ldc, int M, int N)
{
    __shared__ __align__(16) float As[16][68];
    __shared__ __align__(16) float Ws[16][68];
    const int tid = threadIdx.x;
    const int n0 = blockIdx.x * 64;
    const int m0 = blockIdx.y * 64;
    const int ty = tid >> 4, tx = tid & 15;
    const int lrow = tid >> 2;         // 0..63
    const int lk = (tid & 3) << 2;     // 0,4,8,12

    float acc[4][4] = {{0.f}};

    for (int pair = 0; pair < 2; ++pair) {
        const float* A = pair ? A2 : A1;
        const float* W = pair ? W2 : W1;
        const int K = pair ? K2 : K1;
        if (A == nullptr) continue;
        for (int k0 = 0; k0 < K; k0 += 16) {
            float4 av = *reinterpret_cast<const float4*>(
                A + (long long)(m0 + lrow) * K + k0 + lk);
            float4 wv = make_float4(0.f, 0.f, 0.f, 0.f);
            if (n0 + lrow < N)
                wv = *reinterpret_cast<const float4*>(
                    W + (long long)(n0 + lrow) * K + k0 + lk);
            As[lk + 0][lrow] = av.x; As[lk + 1][lrow] = av.y;
            As[lk + 2][lrow] = av.z; As[lk + 3][lrow] = av.w;
            Ws[lk + 0][lrow] = wv.x; Ws[lk + 1][lrow] = wv.y;
            Ws[lk + 2][lrow] = wv.z; Ws[lk + 3][lrow] = wv.w;
            __syncthreads();
#pragma unroll
            for (int kk = 0; kk < 16; ++kk) {
                float4 a4 = *reinterpret_cast<const float4*>(&As[kk][ty * 4]);
                float4 b4 = *reinterpret_cast<const float4*>(&Ws[kk][tx * 4]);
                float ar[4] = {a4.x, a4.y, a4.z, a4.w};
                float br[4] = {b4.x, b4.y, b4.z, b4.w};
#pragma unroll
                for (int i = 0; i < 4; ++i)
#pragma unroll
                    for (int j = 0; j < 4; ++j)
                        acc[i][j] = fmaf(ar[i], br[j], acc[i][j]);
            }
            __syncthreads();
        }
    }

#pragma unroll
    for (int i = 0; i < 4; ++i) {
        const int m = m0 + ty * 4 + i;
#pragma unroll
        for (int j = 0; j < 4; ++j) {
            const int n = n0 + tx * 4 + j;
            if (n >= N) continue;
            float v = acc[i][j];
            if (bias1) v += bias1[n];
            if (bias2) v += bias2[n];
            if (Dadd)  v += Dadd[(long long)m * ldd + n];
            if (ACT == 1) v = tanhf(v);
            if (ACT == 2) v = fmaxf(v, 0.f);
            C[(long long)m * ldc + n] = v;
        }
    }
}

static void gemm(hipStream_t s, int act,
                 const float* A1, const float* W1, int K1,
                 const float* A2, const float* W2, int K2,
                 const float* b1, const float* b2,
                 const float* D, long long ldd,
                 float* C, long long ldc, int M, int N)
{
    dim3 grid((N + 63) / 64, M / 64), blk(256);
    switch (act) {
    case 1: gemm_kernel<1><<<grid, blk, 0, s>>>(A1, W1, K1, A2, W2, K2, b1, b2, D, ldd, C, ldc, M, N); break;
    case 2: gemm_kernel<2><<<grid, blk, 0, s>>>(A1, W1, K1, A2, W2, K2, b1, b2, D, ldd, C, ldc, M, N); break;
    default: gemm_kernel<0><<<grid, blk, 0, s>>>(A1, W1, K1, A2, W2, K2, b1, b2, D, ldd, C, ldc, M, N); break;
    }
}

// ---------------------------------------------------------------------------
// LSTM elementwise cell (torch gate order i,f,g,o).
// ---------------------------------------------------------------------------
__global__ __launch_bounds__(256) void lstm_cell_kernel(
    const float* __restrict__ gates, float* __restrict__ h,
    float* __restrict__ c, float* __restrict__ h_top, int t)
{
    const int idx = blockIdx.x * 256 + threadIdx.x;  // < B*H
    const int b = idx >> 9, hh = idx & 511;
    const float* g = gates + (long long)b * 2048;
    const float gi = g[hh], gf = g[512 + hh], gg = g[1024 + hh], go = g[1536 + hh];
    const float cp = c[idx];
    const float i_ = 1.f / (1.f + expf(-gi));
    const float f_ = 1.f / (1.f + expf(-gf));
    const float o_ = 1.f / (1.f + expf(-go));
    const float cn = f_ * cp + i_ * tanhf(gg);
    const float hn = o_ * tanhf(cn);
    c[idx] = cn;
    h[idx] = hn;
    if (h_top) h_top[((long long)b * T_ + t) * H_ + hh] = hn;
}

// ---------------------------------------------------------------------------
// Fused attention: logits (tanh + dot wa) -> softmax over l -> weighted sum.
// One block (256 threads) per (b,t). ctx is the projected context [B,Lx,H].
// ---------------------------------------------------------------------------
__global__ __launch_bounds__(256) void attend_kernel(
    const float* __restrict__ ctx, int Lx,
    const float* __restrict__ proj,
    const float* __restrict__ wa, const float* __restrict__ ba,
    float* __restrict__ fcat, int off)
{
    __shared__ float p_lds[512];
    __shared__ float wa_lds[512];
    __shared__ float lg[96];
    const int bt = blockIdx.x;
    const int b = bt / T_;
    const int tid = threadIdx.x;

    p_lds[tid] = proj[(long long)bt * H_ + tid];
    p_lds[tid + 256] = proj[(long long)bt * H_ + tid + 256];
    wa_lds[tid] = wa[tid];
    wa_lds[tid + 256] = wa[tid + 256];
    __syncthreads();

    const int wid = tid >> 6, lane = tid & 63;
    const float bav = ba[0];
    for (int l = wid; l < Lx; l += 4) {
        const float* crow = ctx + ((long long)b * Lx + l) * H_;
        float acc = 0.f;
#pragma unroll
        for (int j = 0; j < 8; ++j) {
            const int hp = lane + 64 * j;
            acc += wa_lds[hp] * tanhf(crow[hp] + p_lds[hp]);
        }
        for (int o = 32; o > 0; o >>= 1) acc += __shfl_down(acc, o);
        if (lane == 0) lg[l] = acc + bav;
    }
    __syncthreads();
    if (tid == 0) {
        float m = -1e30f;
        for (int l = 0; l < Lx; ++l) m = fmaxf(m, lg[l]);
        float s = 0.f;
        for (int l = 0; l < Lx; ++l) { const float e = expf(lg[l] - m); lg[l] = e; s += e; }
        const float inv = 1.f / s;
        for (int l = 0; l < Lx; ++l) lg[l] *= inv;
    }
    __syncthreads();
    for (int hp = tid; hp < H_; hp += 256) {
        float acc = 0.f;
        for (int l = 0; l < Lx; ++l)
            acc += lg[l] * ctx[((long long)b * Lx + l) * H_ + hp];
        fcat[(long long)bt * (3 * H_) + off + hp] = acc;
    }
}

// fusion[:, 0:512] = h_top
__global__ __launch_bounds__(256) void copy_fusion_left(
    const float* __restrict__ h_top, float* __restrict__ fusion)
{
    const int idx = blockIdx.x * 256 + threadIdx.x;  // < BT*H
    const int r = idx >> 9, cpos = idx & 511;
    fusion[(long long)r * 1024 + cpos] = h_top[idx];
}

// In-place log_softmax(BETA * x) per row of V_ elements. Block per row.
__global__ __launch_bounds__(256) void log_softmax_kernel(float* __restrict__ out)
{
    __shared__ float red[4];
    __shared__ float bc[2];
    const long long base = (long long)blockIdx.x * V_;
    const int tid = threadIdx.x, lane = tid & 63, wid = tid >> 6;

    float m = -1e30f;
    for (int v = tid; v < V_; v += 256) m = fmaxf(m, out[base + v]);
    for (int o = 32; o > 0; o >>= 1) m = fmaxf(m, __shfl_down(m, o));
    if (lane == 0) red[wid] = m;
    __syncthreads();
    if (tid == 0) {
        float mm = red[0];
        for (int i = 1; i < 4; ++i) mm = fmaxf(mm, red[i]);
        bc[0] = mm;
    }
    __syncthreads();
    m = bc[0];

    float s = 0.f;
    for (int v = tid; v < V_; v += 256) s += expf(BETA_ * (out[base + v] - m));
    for (int o = 32; o > 0; o >>= 1) s += __shfl_down(s, o);
    if (lane == 0) red[wid] = s;
    __syncthreads();
    if (tid == 0) bc[1] = logf(red[0] + red[1] + red[2] + red[3]);
    __syncthreads();
    const float ls = bc[1];
    for (int v = tid; v < V_; v += 256)
        out[base + v] = BETA_ * (out[base + v] - m) - ls;
}

// ---------------------------------------------------------------------------
extern "C" void kernel_launch(void* const* d_in, const int* in_sizes, int n_in,
                              void* d_out_, int out_size, void* d_ws, size_t ws_size,
                              hipStream_t stream)
{
    const float* emb      = (const float*)d_in[0];
    const float* question = (const float*)d_in[1];
    const float* history  = (const float*)d_in[2];
    const float* image    = (const float*)d_in[3];
    const float* h0       = (const float*)d_in[4];
    const float* c0       = (const float*)d_in[5];
    const float* Wih      = (const float*)d_in[6];
    const float* Whh      = (const float*)d_in[7];
    const float* bih      = (const float*)d_in[8];
    const float* bhh      = (const float*)d_in[9];
    const float* Wq    = (const float*)d_in[10]; const float* bq    = (const float*)d_in[11];
    const float* Wansq = (const float*)d_in[12]; const float* bansq = (const float*)d_in[13];
    const float* waq   = (const float*)d_in[14]; const float* baq   = (const float*)d_in[15];
    const float* Wh    = (const float*)d_in[16]; const float* bh    = (const float*)d_in[17];
    const float* Wansh = (const float*)d_in[18]; const float* bansh = (const float*)d_in[19];
    const float* wah   = (const float*)d_in[20]; const float* bah   = (const float*)d_in[21];
    const float* Wi    = (const float*)d_in[22]; const float* bi    = (const float*)d_in[23];
    const float* Wansi = (const float*)d_in[24]; const float* bansi = (const float*)d_in[25];
    const float* wai   = (const float*)d_in[26]; const float* bai   = (const float*)d_in[27];
    const float* Wcat  = (const float*)d_in[28]; const float* bcat  = (const float*)d_in[29];
    const float* Wd1   = (const float*)d_in[30]; const float* bd1   = (const float*)d_in[31];
    const float* Wd2   = (const float*)d_in[32]; const float* bd2   = (const float*)d_in[33];

    float* out = (float*)d_out_;
    float* ws  = (float*)d_ws;

    // ---- workspace layout (floats) ----
    float* q_emb  = ws;                                   // B*LQ*H  = 5,242,880
    float* h_emb  = q_emb  + (long long)B_ * LQ_ * H_;    // B*LH*H  = 10,485,760
    float* i_emb  = h_emb  + (long long)B_ * LH_ * H_;    // B*LI*H  = 6,422,528
    float* gates0 = i_emb  + (long long)B_ * LI_ * H_;    // BT*4H   = 10,485,760 (reused as dec1)
    float* h_top  = gates0 + (long long)BT_ * 4 * H_;     // BT*H    = 2,621,440
    float* st_h   = h_top  + (long long)BT_ * H_;         // 2*B*H
    float* st_c   = st_h   + 2LL * B_ * H_;               // 2*B*H
    float* gtmp   = st_c   + 2LL * B_ * H_;               // B*4H
    // total ~145 MB

    // ---- transient buffers inside d_out's lps region (dead before dec2) ----
    float* proj   = out;                                  // BT*H
    float* fcat   = out  + (long long)BT_ * H_;           // BT*3H
    float* fusion = fcat + (long long)BT_ * 3 * H_;       // BT*2H

    // 1) context projections (timestep-invariant)
    gemm(stream, 0, question, Wq, 2 * H_, nullptr, nullptr, 0, bq, nullptr,
         nullptr, 0, q_emb, H_, B_ * LQ_, H_);
    gemm(stream, 0, history, Wh, 2 * H_, nullptr, nullptr, 0, bh, nullptr,
         nullptr, 0, h_emb, H_, B_ * LH_, H_);
    gemm(stream, 0, image, Wi, 2 * H_, nullptr, nullptr, 0, bi, nullptr,
         nullptr, 0, i_emb, H_, B_ * LI_, H_);

    // 2) layer-0 input gates for all timesteps: emb @ Wih0^T + bih0 + bhh0
    gemm(stream, 0, emb, Wih, H_, nullptr, nullptr, 0, bih, bhh,
         nullptr, 0, gates0, 4 * H_, BT_, 4 * H_);

    // 3) init recurrent state
    hipMemcpyAsync(st_h, h0, 2LL * B_ * H_ * sizeof(float), hipMemcpyDeviceToDevice, stream);
    hipMemcpyAsync(st_c, c0, 2LL * B_ * H_ * sizeof(float), hipMemcpyDeviceToDevice, stream);

    const float* Wih1 = Wih + 4LL * H_ * H_;
    const float* Whh0 = Whh;
    const float* Whh1 = Whh + 4LL * H_ * H_;
    const float* bih1 = bih + 4 * H_;
    const float* bhh1 = bhh + 4 * H_;

    // 4) sequential LSTM over T
    for (int t = 0; t < T_; ++t) {
        // layer 0: gtmp = st_h0 @ Whh0^T + gates0[:, t, :]
        gemm(stream, 0, st_h, Whh0, H_, nullptr, nullptr, 0, nullptr, nullptr,
             gates0 + (long long)t * 4 * H_, (long long)T_ * 4 * H_,
             gtmp, 4 * H_, B_, 4 * H_);
        lstm_cell_kernel<<<dim3(B_ * H_ / 256), dim3(256), 0, stream>>>(
            gtmp, st_h, st_c, nullptr, 0);
        // layer 1: gtmp = h0_t @ Wih1^T + h1_prev @ Whh1^T + bih1 + bhh1
        gemm(stream, 0, st_h, Wih1, H_, st_h + (long long)B_ * H_, Whh1, H_,
             bih1, bhh1, nullptr, 0, gtmp, 4 * H_, B_, 4 * H_);
        lstm_cell_kernel<<<dim3(B_ * H_ / 256), dim3(256), 0, stream>>>(
            gtmp, st_h + (long long)B_ * H_, st_c + (long long)B_ * H_, h_top, t);
    }

    // 5) attentions (batched over all b,t)
    gemm(stream, 0, h_top, Wansq, H_, nullptr, nullptr, 0, bansq, nullptr,
         nullptr, 0, proj, H_, BT_, H_);
    attend_kernel<<<dim3(BT_), dim3(256), 0, stream>>>(q_emb, LQ_, proj, waq, baq, fcat, 0);

    gemm(stream, 0, h_top, Wansh, H_, nullptr, nullptr, 0, bansh, nullptr,
         nullptr, 0, proj, H_, BT_, H_);
    attend_kernel<<<dim3(BT_), dim3(256), 0, stream>>>(h_emb, LH_, proj, wah, bah, fcat, 512);

    gemm(stream, 0, h_top, Wansi, H_, nullptr, nullptr, 0, bansi, nullptr,
         nullptr, 0, proj, H_, BT_, H_);
    attend_kernel<<<dim3(BT_), dim3(256), 0, stream>>>(i_emb, LI_, proj, wai, bai, fcat, 1024);

    // 6) fusion = [h_top, tanh(fcat @ Wcat^T + bcat)]
    copy_fusion_left<<<dim3(BT_ * H_ / 256), dim3(256), 0, stream>>>(h_top, fusion);
    gemm(stream, 1, fcat, Wcat, 3 * H_, nullptr, nullptr, 0, bcat, nullptr,
         nullptr, 0, fusion + H_, 2 * H_, BT_, H_);

    // 7) decoder
    float* dec1 = gates0;  // reuse (dead after LSTM)
    gemm(stream, 2, fusion, Wd1, 2 * H_, nullptr, nullptr, 0, bd1, nullptr,
         nullptr, 0, dec1, 4 * H_, BT_, 4 * H_);
    gemm(stream, 0, dec1, Wd2, 4 * H_, nullptr, nullptr, 0, bd2, nullptr,
         nullptr, 0, out, V_, BT_, V_);

    // 8) in-place log_softmax(BETA * dec)
    log_softmax_kernel<<<dim3(BT_), dim3(256), 0, stream>>>(out);

    // 9) tail: hT, cT  (st_h and st_c are contiguous)
    hipMemcpyAsync(out + (long long)BT_ * V_, st_h,
                   4LL * B_ * H_ * sizeof(float), hipMemcpyDeviceToDevice, stream);
}

// Round 2
// 3079.107 us; speedup vs baseline: 2.2423x; 2.2423x over previous
//
#include <hip/hip_runtime.h>
#include <cmath>

#define B_ 256
#define T_ 20
#define H_ 512
#define V_ 8964
#define LQ_ 40
#define LH_ 80
#define LI_ 49
#define BT_ (B_ * T_)   // 5120
#define NPAD_ 9088      // V_ padded to multiple of 128
#define BETA_ 3.0f

typedef __attribute__((ext_vector_type(8))) short bf16x8;
typedef __attribute__((ext_vector_type(4))) float f32x4;
typedef __attribute__((ext_vector_type(8))) unsigned short u16x8;

static __device__ __forceinline__ unsigned short f2bf(float f) {
    union { float f; unsigned u; } v; v.f = f;
    unsigned r = v.u + 0x7FFF + ((v.u >> 16) & 1);
    return (unsigned short)(r >> 16);
}
static __device__ __forceinline__ float bf2f(unsigned short u) {
    union { unsigned u; float f; } v; v.u = ((unsigned)u) << 16;
    return v.f;
}

// ---------------------------------------------------------------------------
// f32 -> bf16 convert with optional row padding (rows >= srcRows get zeros).
// cols % 8 == 0. One thread handles 8 elements.
// ---------------------------------------------------------------------------
__global__ __launch_bounds__(256) void cvt_kernel(
    const float* __restrict__ src, unsigned short* __restrict__ dst,
    long long srcRows, long long cols, long long dstRows)
{
    const long long total = dstRows * cols;
    const long long e0 = ((long long)blockIdx.x * 256 + threadIdx.x) * 8;
    if (e0 >= total) return;
    const long long row = e0 / cols;
    u16x8 v;
    if (row < srcRows) {
        float4 a = *reinterpret_cast<const float4*>(src + e0);
        float4 b = *reinterpret_cast<const float4*>(src + e0 + 4);
        v[0] = f2bf(a.x); v[1] = f2bf(a.y); v[2] = f2bf(a.z); v[3] = f2bf(a.w);
        v[4] = f2bf(b.x); v[5] = f2bf(b.y); v[6] = f2bf(b.z); v[7] = f2bf(b.w);
    } else {
        v = (u16x8)0;
    }
    *reinterpret_cast<u16x8*>(dst + e0) = v;
}

static void cvt(hipStream_t s, const float* src, unsigned short* dst,
                long long srcRows, long long cols, long long dstRows)
{
    long long total = dstRows * cols;
    cvt_kernel<<<dim3((unsigned)((total / 8 + 255) / 256)), dim3(256), 0, s>>>(
        src, dst, srcRows, cols, dstRows);
}

// ---------------------------------------------------------------------------
// bf16 MFMA GEMM: C[m,n] = act(A[m,:]·W[n,:] + bias1[n] + bias2[n])
// A [M,K] bf16 row-major, W [N,K] bf16 row-major. M%128==0, K%32==0,
// grid.x covers N padded to 128; stores guarded to col < Nreal.
// 128x128 tile, BK=32, 4 waves (each 64x64 via 4x4 16x16 fragments),
// register-staged double-buffered LDS.
// ACT: 0 none, 1 tanh, 2 relu. OUTBF: 1 -> bf16 output, 0 -> fp32.
// ---------------------------------------------------------------------------
template <int ACT, int OUTBF>
__global__ __launch_bounds__(256, 2) void mfma_gemm(
    const unsigned short* __restrict__ A, const unsigned short* __restrict__ W,
    const float* __restrict__ bias1, const float* __restrict__ bias2,
    void* __restrict__ C, long long ldc, int Nreal, int K)
{
    __shared__ __align__(16) unsigned short As[128][32];
    __shared__ __align__(16) unsigned short Bs[128][32];
    const int tid = threadIdx.x;
    const int lane = tid & 63;
    const int wave = tid >> 6;
    const int wm = wave >> 1, wn = wave & 1;
    const int m0 = blockIdx.y * 128, n0 = blockIdx.x * 128;
    const int r = tid >> 2;            // 0..63
    const int ck = (tid & 3) * 8;      // k element offset (0,8,16,24)

    const unsigned short* Ap = A + (long long)m0 * K;
    const unsigned short* Wp = W + (long long)n0 * K;

    f32x4 acc[4][4] = {};

    int4 ra0, ra1, rb0, rb1;
    {
        ra0 = *reinterpret_cast<const int4*>(Ap + (long long)r * K + ck);
        ra1 = *reinterpret_cast<const int4*>(Ap + (long long)(r + 64) * K + ck);
        rb0 = *reinterpret_cast<const int4*>(Wp + (long long)r * K + ck);
        rb1 = *reinterpret_cast<const int4*>(Wp + (long long)(r + 64) * K + ck);
    }

    for (int k0 = 0; k0 < K; k0 += 32) {
        __syncthreads();
        *reinterpret_cast<int4*>(&As[r][ck]) = ra0;
        *reinterpret_cast<int4*>(&As[r + 64][ck]) = ra1;
        *reinterpret_cast<int4*>(&Bs[r][ck]) = rb0;
        *reinterpret_cast<int4*>(&Bs[r + 64][ck]) = rb1;
        __syncthreads();
        if (k0 + 32 < K) {
            const int kn = k0 + 32 + ck;
            ra0 = *reinterpret_cast<const int4*>(Ap + (long long)r * K + kn);
            ra1 = *reinterpret_cast<const int4*>(Ap + (long long)(r + 64) * K + kn);
            rb0 = *reinterpret_cast<const int4*>(Wp + (long long)r * K + kn);
            rb1 = *reinterpret_cast<const int4*>(Wp + (long long)(r + 64) * K + kn);
        }
        const int lr = lane & 15, lk = (lane >> 4) * 8;
        bf16x8 af[4], bfr[4];
#pragma unroll
        for (int i = 0; i < 4; ++i) {
            af[i]  = *reinterpret_cast<const bf16x8*>(&As[wm * 64 + i * 16 + lr][lk]);
            bfr[i] = *reinterpret_cast<const bf16x8*>(&Bs[wn * 64 + i * 16 + lr][lk]);
        }
#pragma unroll
        for (int i = 0; i < 4; ++i)
#pragma unroll
            for (int j = 0; j < 4; ++j)
                acc[i][j] = __builtin_amdgcn_mfma_f32_16x16x32_bf16(
                    af[i], bfr[j], acc[i][j], 0, 0, 0);
    }

    // epilogue: D mapping col=lane&15, row=(lane>>4)*4+reg  [measured m89/m91]
    const int lr = lane & 15, lrow4 = (lane >> 4) * 4;
#pragma unroll
    for (int j = 0; j < 4; ++j) {
        const int col = n0 + wn * 64 + j * 16 + lr;
        if (col >= Nreal) continue;
        float bsum = 0.f;
        if (bias1) bsum += bias1[col];
        if (bias2) bsum += bias2[col];
#pragma unroll
        for (int i = 0; i < 4; ++i) {
#pragma unroll
            for (int rr = 0; rr < 4; ++rr) {
                const int row = m0 + wm * 64 + i * 16 + lrow4 + rr;
                float v = acc[i][j][rr] + bsum;
                if (ACT == 1) v = tanhf(v);
                if (ACT == 2) v = fmaxf(v, 0.f);
                if (OUTBF)
                    ((unsigned short*)C)[(long long)row * ldc + col] = f2bf(v);
                else
                    ((float*)C)[(long long)row * ldc + col] = v;
            }
        }
    }
}

static void mgemm(hipStream_t s, int act, int outbf,
                  const unsigned short* A, const unsigned short* W,
                  const float* b1, const float* b2,
                  void* C, long long ldc, int M, int Nreal, int K)
{
    dim3 grid((Nreal + 127) / 128, M / 128), blk(256);
    if (outbf) {
        switch (act) {
        case 1: mfma_gemm<1,1><<<grid, blk, 0, s>>>(A, W, b1, b2, C, ldc, Nreal, K); break;
        case 2: mfma_gemm<2,1><<<grid, blk, 0, s>>>(A, W, b1, b2, C, ldc, Nreal, K); break;
        default: mfma_gemm<0,1><<<grid, blk, 0, s>>>(A, W, b1, b2, C, ldc, Nreal, K); break;
        }
    } else {
        switch (act) {
        case 1: mfma_gemm<1,0><<<grid, blk, 0, s>>>(A, W, b1, b2, C, ldc, Nreal, K); break;
        case 2: mfma_gemm<2,0><<<grid, blk, 0, s>>>(A, W, b1, b2, C, ldc, Nreal, K); break;
        default: mfma_gemm<0,0><<<grid, blk, 0, s>>>(A, W, b1, b2, C, ldc, Nreal, K); break;
        }
    }
}

// ---------------------------------------------------------------------------
// fp32 vector GEMM (kept for the small sequential LSTM-step GEMMs, M=256).
// C[m,n] = A1[m,:]·W1[n,:] + A2[m,:]·W2[n,:] + bias1[n] + bias2[n] + D[m,n]
// ---------------------------------------------------------------------------
__global__ __launch_bounds__(256) void gemm_f32_kernel(
    const float* __restrict__ A1, const float* __restrict__ W1, int K1,
    const float* __restrict__ A2, const float* __restrict__ W2, int K2,
    const float* __restrict__ bias1, const float* __restrict__ bias2,
    const float* __restrict__ Dadd, long long ldd,
    float* __restrict__ C, long long ldc, int M, int N)
{
    __shared__ __align__(16) float As[16][68];
    __shared__ __align__(16) float Ws[16][68];
    const int tid = threadIdx.x;
    const int n0 = blockIdx.x * 64;
    const int m0 = blockIdx.y * 64;
    const int ty = tid >> 4, tx = tid & 15;
    const int lrow = tid >> 2;
    const int lk = (tid & 3) << 2;

    float acc[4][4] = {{0.f}};

    for (int pair = 0; pair < 2; ++pair) {
        const float* A = pair ? A2 : A1;
        const float* W = pair ? W2 : W1;
        const int K = pair ? K2 : K1;
        if (A == nullptr) continue;
        for (int k0 = 0; k0 < K; k0 += 16) {
            float4 av = *reinterpret_cast<const float4*>(
                A + (long long)(m0 + lrow) * K + k0 + lk);
            float4 wv = *reinterpret_cast<const float4*>(
                W + (long long)(n0 + lrow) * K + k0 + lk);
            As[lk + 0][lrow] = av.x; As[lk + 1][lrow] = av.y;
            As[lk + 2][lrow] = av.z; As[lk + 3][lrow] = av.w;
            Ws[lk + 0][lrow] = wv.x; Ws[lk + 1][lrow] = wv.y;
            Ws[lk + 2][lrow] = wv.z; Ws[lk + 3][lrow] = wv.w;
            __syncthreads();
#pragma unroll
            for (int kk = 0; kk < 16; ++kk) {
                float4 a4 = *reinterpret_cast<const float4*>(&As[kk][ty * 4]);
                float4 b4 = *reinterpret_cast<const float4*>(&Ws[kk][tx * 4]);
                float ar[4] = {a4.x, a4.y, a4.z, a4.w};
                float br[4] = {b4.x, b4.y, b4.z, b4.w};
#pragma unroll
                for (int i = 0; i < 4; ++i)
#pragma unroll
                    for (int j = 0; j < 4; ++j)
                        acc[i][j] = fmaf(ar[i], br[j], acc[i][j]);
            }
            __syncthreads();
        }
    }

#pragma unroll
    for (int i = 0; i < 4; ++i) {
        const int m = m0 + ty * 4 + i;
#pragma unroll
        for (int j = 0; j < 4; ++j) {
            const int n = n0 + tx * 4 + j;
            float v = acc[i][j];
            if (bias1) v += bias1[n];
            if (bias2) v += bias2[n];
            if (Dadd)  v += Dadd[(long long)m * ldd + n];
            C[(long long)m * ldc + n] = v;
        }
    }
}

// ---------------------------------------------------------------------------
// LSTM elementwise cell (torch gate order i,f,g,o).
// ---------------------------------------------------------------------------
__global__ __launch_bounds__(256) void lstm_cell_kernel(
    const float* __restrict__ gates, float* __restrict__ h,
    float* __restrict__ c, float* __restrict__ h_top, int t)
{
    const int idx = blockIdx.x * 256 + threadIdx.x;  // < B*H
    const int b = idx >> 9, hh = idx & 511;
    const float* g = gates + (long long)b * 2048;
    const float gi = g[hh], gf = g[512 + hh], gg = g[1024 + hh], go = g[1536 + hh];
    const float cp = c[idx];
    const float i_ = 1.f / (1.f + expf(-gi));
    const float f_ = 1.f / (1.f + expf(-gf));
    const float o_ = 1.f / (1.f + expf(-go));
    const float cn = f_ * cp + i_ * tanhf(gg);
    const float hn = o_ * tanhf(cn);
    c[idx] = cn;
    h[idx] = hn;
    if (h_top) h_top[((long long)b * T_ + t) * H_ + hh] = hn;
}

// ---------------------------------------------------------------------------
// Fused attention over bf16 ctx: logits -> softmax -> weighted sum (bf16 out).
// One block (256 threads) per (b,t).
// ---------------------------------------------------------------------------
__global__ __launch_bounds__(256) void attend_kernel(
    const unsigned short* __restrict__ ctx, int Lx,
    const float* __restrict__ proj,
    const float* __restrict__ wa, const float* __restrict__ ba,
    unsigned short* __restrict__ fcat, int off)
{
    __shared__ float p_lds[512];
    __shared__ float wa_lds[512];
    __shared__ float lg[96];
    const int bt = blockIdx.x;
    const int b = bt / T_;
    const int tid = threadIdx.x;

    p_lds[tid] = proj[(long long)bt * H_ + tid];
    p_lds[tid + 256] = proj[(long long)bt * H_ + tid + 256];
    wa_lds[tid] = wa[tid];
    wa_lds[tid + 256] = wa[tid + 256];
    __syncthreads();

    const int wid = tid >> 6, lane = tid & 63;
    const float bav = ba[0];
    for (int l = wid; l < Lx; l += 4) {
        const unsigned short* crow = ctx + ((long long)b * Lx + l) * H_;
        float acc = 0.f;
#pragma unroll
        for (int j = 0; j < 8; ++j) {
            const int hp = lane + 64 * j;
            acc += wa_lds[hp] * tanhf(bf2f(crow[hp]) + p_lds[hp]);
        }
        for (int o = 32; o > 0; o >>= 1) acc += __shfl_down(acc, o);
        if (lane == 0) lg[l] = acc + bav;
    }
    __syncthreads();
    if (tid == 0) {
        float m = -1e30f;
        for (int l = 0; l < Lx; ++l) m = fmaxf(m, lg[l]);
        float s = 0.f;
        for (int l = 0; l < Lx; ++l) { const float e = expf(lg[l] - m); lg[l] = e; s += e; }
        const float inv = 1.f / s;
        for (int l = 0; l < Lx; ++l) lg[l] *= inv;
    }
    __syncthreads();
    for (int hp = tid; hp < H_; hp += 256) {
        float acc = 0.f;
        for (int l = 0; l < Lx; ++l)
            acc += lg[l] * bf2f(ctx[((long long)b * Lx + l) * H_ + hp]);
        fcat[(long long)bt * (3 * H_) + off + hp] = f2bf(acc);
    }
}

// fusion_bf[:, 0:512] = bf16(h_top)
__global__ __launch_bounds__(256) void copy_fusion_left(
    const float* __restrict__ h_top, unsigned short* __restrict__ fusion)
{
    const int idx = blockIdx.x * 256 + threadIdx.x;  // < BT*H
    const int r = idx >> 9, cpos = idx & 511;
    fusion[(long long)r * 1024 + cpos] = f2bf(h_top[idx]);
}

// In-place log_softmax(BETA * x) per row of V_. Block per row.
__global__ __launch_bounds__(256) void log_softmax_kernel(float* __restrict__ out)
{
    __shared__ float red[4];
    __shared__ float bc[2];
    const long long base = (long long)blockIdx.x * V_;
    const int tid = threadIdx.x, lane = tid & 63, wid = tid >> 6;

    float m = -1e30f;
    for (int v = tid; v < V_; v += 256) m = fmaxf(m, out[base + v]);
    for (int o = 32; o > 0; o >>= 1) m = fmaxf(m, __shfl_down(m, o));
    if (lane == 0) red[wid] = m;
    __syncthreads();
    if (tid == 0) {
        float mm = red[0];
        for (int i = 1; i < 4; ++i) mm = fmaxf(mm, red[i]);
        bc[0] = mm;
    }
    __syncthreads();
    m = bc[0];

    float s = 0.f;
    for (int v = tid; v < V_; v += 256) s += expf(BETA_ * (out[base + v] - m));
    for (int o = 32; o > 0; o >>= 1) s += __shfl_down(s, o);
    if (lane == 0) red[wid] = s;
    __syncthreads();
    if (tid == 0) bc[1] = logf(red[0] + red[1] + red[2] + red[3]);
    __syncthreads();
    const float ls = bc[1];
    for (int v = tid; v < V_; v += 256)
        out[base + v] = BETA_ * (out[base + v] - m) - ls;
}

// ---------------------------------------------------------------------------
extern "C" void kernel_launch(void* const* d_in, const int* in_sizes, int n_in,
                              void* d_out_, int out_size, void* d_ws, size_t ws_size,
                              hipStream_t stream)
{
    const float* emb      = (const float*)d_in[0];
    const float* question = (const float*)d_in[1];
    const float* history  = (const float*)d_in[2];
    const float* image    = (const float*)d_in[3];
    const float* h0       = (const float*)d_in[4];
    const float* c0       = (const float*)d_in[5];
    const float* Wih      = (const float*)d_in[6];
    const float* Whh      = (const float*)d_in[7];
    const float* bih      = (const float*)d_in[8];
    const float* bhh      = (const float*)d_in[9];
    const float* Wq    = (const float*)d_in[10]; const float* bq    = (const float*)d_in[11];
    const float* Wansq = (const float*)d_in[12]; const float* bansq = (const float*)d_in[13];
    const float* waq   = (const float*)d_in[14]; const float* baq   = (const float*)d_in[15];
    const float* Wh    = (const float*)d_in[16]; const float* bh    = (const float*)d_in[17];
    const float* Wansh = (const float*)d_in[18]; const float* bansh = (const float*)d_in[19];
    const float* wah   = (const float*)d_in[20]; const float* bah   = (const float*)d_in[21];
    const float* Wi    = (const float*)d_in[22]; const float* bi    = (const float*)d_in[23];
    const float* Wansi = (const float*)d_in[24]; const float* bansi = (const float*)d_in[25];
    const float* wai   = (const float*)d_in[26]; const float* bai   = (const float*)d_in[27];
    const float* Wcat  = (const float*)d_in[28]; const float* bcat  = (const float*)d_in[29];
    const float* Wd1   = (const float*)d_in[30]; const float* bd1   = (const float*)d_in[31];
    const float* Wd2   = (const float*)d_in[32]; const float* bd2   = (const float*)d_in[33];

    float* out = (float*)d_out_;
    float* ws  = (float*)d_ws;

    // ---- persistent workspace layout ----
    float* gates0 = ws;                                    // BT*4H fp32
    float* h_top  = gates0 + (long long)BT_ * 4 * H_;      // BT*H fp32
    float* st_h   = h_top + (long long)BT_ * H_;           // 2*B*H fp32
    float* st_c   = st_h + 2LL * B_ * H_;                  // 2*B*H fp32
    float* gtmp   = st_c + 2LL * B_ * H_;                  // B*4H fp32
    unsigned short* q_emb_bf = (unsigned short*)(gtmp + (long long)B_ * 4 * H_); // B*LQ*H
    unsigned short* h_emb_bf = q_emb_bf + (long long)B_ * LQ_ * H_;              // B*LH*H
    unsigned short* i_emb_bf = h_emb_bf + (long long)B_ * LH_ * H_;              // B*LI*H
    unsigned short* dec1_bf  = i_emb_bf + (long long)B_ * LI_ * H_;              // BT*4H
    unsigned short* Wd2p_bf  = dec1_bf + (long long)BT_ * 4 * H_;                // NPAD*4H

    // ---- phase-A scratch inside d_out (dead before phase C) ----
    unsigned short* q_bf    = (unsigned short*)out;                 // B*LQ*2H
    unsigned short* hi_bf   = q_bf  + (long long)B_ * LQ_ * 2 * H_; // B*LH*2H
    unsigned short* im_bf   = hi_bf + (long long)B_ * LH_ * 2 * H_; // B*LI*2H
    unsigned short* Wq_bf   = im_bf + (long long)B_ * LI_ * 2 * H_; // H*2H
    unsigned short* Wh_bf   = Wq_bf + (long long)H_ * 2 * H_;
    unsigned short* Wi_bf   = Wh_bf + (long long)H_ * 2 * H_;
    unsigned short* emb_bf  = Wi_bf + (long long)H_ * 2 * H_;       // BT*H
    unsigned short* Wih0_bf = emb_bf + (long long)BT_ * H_;         // 4H*H

    // 1) converts for phase A
    cvt(stream, question, q_bf, 1, (long long)B_ * LQ_ * 2 * H_, 1);
    cvt(stream, history,  hi_bf, 1, (long long)B_ * LH_ * 2 * H_, 1);
    cvt(stream, image,    im_bf, 1, (long long)B_ * LI_ * 2 * H_, 1);
    cvt(stream, Wq, Wq_bf, 1, (long long)H_ * 2 * H_, 1);
    cvt(stream, Wh, Wh_bf, 1, (long long)H_ * 2 * H_, 1);
    cvt(stream, Wi, Wi_bf, 1, (long long)H_ * 2 * H_, 1);
    cvt(stream, emb, emb_bf, 1, (long long)BT_ * H_, 1);
    cvt(stream, Wih, Wih0_bf, 1, (long long)4 * H_ * H_, 1);

    // 2) context projections (bf16 out) + layer-0 input gates (fp32 out)
    mgemm(stream, 0, 1, q_bf, Wq_bf, bq, nullptr, q_emb_bf, H_, B_ * LQ_, H_, 2 * H_);
    mgemm(stream, 0, 1, hi_bf, Wh_bf, bh, nullptr, h_emb_bf, H_, B_ * LH_, H_, 2 * H_);
    mgemm(stream, 0, 1, im_bf, Wi_bf, bi, nullptr, i_emb_bf, H_, B_ * LI_, H_, 2 * H_);
    mgemm(stream, 0, 0, emb_bf, Wih0_bf, bih, bhh, gates0, 4 * H_, BT_, 4 * H_, H_);

    // 3) init recurrent state
    hipMemcpyAsync(st_h, h0, 2LL * B_ * H_ * sizeof(float), hipMemcpyDeviceToDevice, stream);
    hipMemcpyAsync(st_c, c0, 2LL * B_ * H_ * sizeof(float), hipMemcpyDeviceToDevice, stream);

    const float* Wih1 = Wih + 4LL * H_ * H_;
    const float* Whh0 = Whh;
    const float* Whh1 = Whh + 4LL * H_ * H_;
    const float* bih1 = bih + 4 * H_;
    const float* bhh1 = bhh + 4 * H_;

    // 4) sequential LSTM over T (fp32)
    for (int t = 0; t < T_; ++t) {
        gemm_f32_kernel<<<dim3(32, 4), dim3(256), 0, stream>>>(
            st_h, Whh0, H_, nullptr, nullptr, 0, nullptr, nullptr,
            gates0 + (long long)t * 4 * H_, (long long)T_ * 4 * H_,
            gtmp, 4 * H_, B_, 4 * H_);
        lstm_cell_kernel<<<dim3(B_ * H_ / 256), dim3(256), 0, stream>>>(
            gtmp, st_h, st_c, nullptr, 0);
        gemm_f32_kernel<<<dim3(32, 4), dim3(256), 0, stream>>>(
            st_h, Wih1, H_, st_h + (long long)B_ * H_, Whh1, H_,
            bih1, bhh1, nullptr, 0, gtmp, 4 * H_, B_, 4 * H_);
        lstm_cell_kernel<<<dim3(B_ * H_ / 256), dim3(256), 0, stream>>>(
            gtmp, st_h + (long long)B_ * H_, st_c + (long long)B_ * H_, h_top, t);
    }

    // ---- phase-C scratch inside d_out (phase-A scratch now dead) ----
    float* proj = out;                                              // BT*H fp32
    unsigned short* h_top_bf  = (unsigned short*)(proj + (long long)BT_ * H_); // BT*H
    unsigned short* fcat_bf   = h_top_bf + (long long)BT_ * H_;     // BT*3H
    unsigned short* fusion_bf = fcat_bf + (long long)BT_ * 3 * H_;  // BT*2H
    unsigned short* Wansq_bf  = fusion_bf + (long long)BT_ * 2 * H_;
    unsigned short* Wansh_bf  = Wansq_bf + (long long)H_ * H_;
    unsigned short* Wansi_bf  = Wansh_bf + (long long)H_ * H_;
    unsigned short* Wcat_bf   = Wansi_bf + (long long)H_ * H_;      // H*3H
    unsigned short* Wd1_bf    = Wcat_bf + (long long)H_ * 3 * H_;   // 4H*2H

    // 5) converts for phase C
    cvt(stream, h_top, h_top_bf, 1, (long long)BT_ * H_, 1);
    cvt(stream, Wansq, Wansq_bf, 1, (long long)H_ * H_, 1);
    cvt(stream, Wansh, Wansh_bf, 1, (long long)H_ * H_, 1);
    cvt(stream, Wansi, Wansi_bf, 1, (long long)H_ * H_, 1);
    cvt(stream, Wcat, Wcat_bf, 1, (long long)H_ * 3 * H_, 1);
    cvt(stream, Wd1, Wd1_bf, 1, (long long)4 * H_ * 2 * H_, 1);
    cvt(stream, Wd2, Wd2p_bf, V_, (long long)4 * H_, NPAD_);

    // 6) attentions
    mgemm(stream, 0, 0, h_top_bf, Wansq_bf, bansq, nullptr, proj, H_, BT_, H_, H_);
    attend_kernel<<<dim3(BT_), dim3(256), 0, stream>>>(q_emb_bf, LQ_, proj, waq, baq, fcat_bf, 0);
    mgemm(stream, 0, 0, h_top_bf, Wansh_bf, bansh, nullptr, proj, H_, BT_, H_, H_);
    attend_kernel<<<dim3(BT_), dim3(256), 0, stream>>>(h_emb_bf, LH_, proj, wah, bah, fcat_bf, 512);
    mgemm(stream, 0, 0, h_top_bf, Wansi_bf, bansi, nullptr, proj, H_, BT_, H_, H_);
    attend_kernel<<<dim3(BT_), dim3(256), 0, stream>>>(i_emb_bf, LI_, proj, wai, bai, fcat_bf, 1024);

    // 7) fusion = [bf16(h_top), tanh(fcat @ Wcat^T + bcat)]
    copy_fusion_left<<<dim3(BT_ * H_ / 256), dim3(256), 0, stream>>>(h_top, fusion_bf);
    mgemm(stream, 1, 1, fcat_bf, Wcat_bf, bcat, nullptr, fusion_bf + H_, 2 * H_, BT_, H_, 3 * H_);

    // 8) decoder
    mgemm(stream, 2, 1, fusion_bf, Wd1_bf, bd1, nullptr, dec1_bf, 4 * H_, BT_, 4 * H_, 2 * H_);
    mgemm(stream, 0, 0, dec1_bf, Wd2p_bf, bd2, nullptr, out, V_, BT_, V_, 4 * H_);

    // 9) in-place log_softmax(BETA * dec)
    log_softmax_kernel<<<dim3(BT_), dim3(256), 0, stream>>>(out);

    // 10) tail: hT, cT
    hipMemcpyAsync(out + (long long)BT_ * V_, st_h,
                   4LL * B_ * H_ * sizeof(float), hipMemcpyDeviceToDevice, stream);
}

// Round 3
// 1899.562 us; speedup vs baseline: 3.6347x; 1.6210x over previous
//
#include <hip/hip_runtime.h>
#include <cmath>

#define B_ 256
#define T_ 20
#define H_ 512
#define V_ 8964
#define LQ_ 40
#define LH_ 80
#define LI_ 49
#define BT_ (B_ * T_)   // 5120
#define BH_ (B_ * H_)   // 131072
#define NPAD_ 9088      // V_ padded to multiple of 128
#define BETA_ 3.0f

typedef __attribute__((ext_vector_type(8))) short bf16x8;
typedef __attribute__((ext_vector_type(4))) float f32x4;
typedef __attribute__((ext_vector_type(8))) unsigned short u16x8;

static __device__ __forceinline__ unsigned short f2bf(float f) {
    union { float f; unsigned u; } v; v.f = f;
    unsigned r = v.u + 0x7FFF + ((v.u >> 16) & 1);
    return (unsigned short)(r >> 16);
}
static __device__ __forceinline__ float bf2f(unsigned short u) {
    union { unsigned u; float f; } v; v.u = ((unsigned)u) << 16;
    return v.f;
}

// ---------------------------------------------------------------------------
// f32 -> bf16 convert with optional row padding (rows >= srcRows get zeros).
// ---------------------------------------------------------------------------
__global__ __launch_bounds__(256) void cvt_kernel(
    const float* __restrict__ src, unsigned short* __restrict__ dst,
    long long srcRows, long long cols, long long dstRows)
{
    const long long total = dstRows * cols;
    const long long e0 = ((long long)blockIdx.x * 256 + threadIdx.x) * 8;
    if (e0 >= total) return;
    const long long row = e0 / cols;
    u16x8 v;
    if (row < srcRows) {
        float4 a = *reinterpret_cast<const float4*>(src + e0);
        float4 b = *reinterpret_cast<const float4*>(src + e0 + 4);
        v[0] = f2bf(a.x); v[1] = f2bf(a.y); v[2] = f2bf(a.z); v[3] = f2bf(a.w);
        v[4] = f2bf(b.x); v[5] = f2bf(b.y); v[6] = f2bf(b.z); v[7] = f2bf(b.w);
    } else {
        v = (u16x8)0;
    }
    *reinterpret_cast<u16x8*>(dst + e0) = v;
}

static void cvt(hipStream_t s, const float* src, unsigned short* dst,
                long long srcRows, long long cols, long long dstRows)
{
    long long total = dstRows * cols;
    cvt_kernel<<<dim3((unsigned)((total / 8 + 255) / 256)), dim3(256), 0, s>>>(
        src, dst, srcRows, cols, dstRows);
}

// ---------------------------------------------------------------------------
// Gate-interleaving permuted convert for LSTM weights [2048][512]:
// dst row n' = 4h+g  <-  src row g*512+h. bf16 out.
// ---------------------------------------------------------------------------
__global__ __launch_bounds__(256) void cvt_perm_kernel(
    const float* __restrict__ src, unsigned short* __restrict__ dst)
{
    const long long e0 = ((long long)blockIdx.x * 256 + threadIdx.x) * 8;
    if (e0 >= 2048LL * 512) return;
    const int drow = (int)(e0 >> 9);
    const int col = (int)(e0 & 511);
    const int srow = ((drow & 3) << 9) | (drow >> 2);
    const float* sp = src + (long long)srow * 512 + col;
    float4 a = *reinterpret_cast<const float4*>(sp);
    float4 b = *reinterpret_cast<const float4*>(sp + 4);
    u16x8 v;
    v[0] = f2bf(a.x); v[1] = f2bf(a.y); v[2] = f2bf(a.z); v[3] = f2bf(a.w);
    v[4] = f2bf(b.x); v[5] = f2bf(b.y); v[6] = f2bf(b.z); v[7] = f2bf(b.w);
    *reinterpret_cast<u16x8*>(dst + e0) = v;
}

// dst[n'] = b1[orig(n')] + b2[orig(n')], n' in [0,2048)
__global__ __launch_bounds__(256) void bias_perm_kernel(
    const float* __restrict__ b1, const float* __restrict__ b2,
    float* __restrict__ dst)
{
    const int n = blockIdx.x * 256 + threadIdx.x;
    if (n < 2048) {
        const int orig = ((n & 3) << 9) | (n >> 2);
        dst[n] = b1[orig] + b2[orig];
    }
}

// ---------------------------------------------------------------------------
// bf16 MFMA GEMM: C[m,n] = act(A[m,:]·W[n,:] + bias1[n] + bias2[n])
// 128x128 tile, BK=32, 4 waves, register-prefetch LDS staging.
// Bijective XCD swizzle (m204) on the linearized block id for L2 locality.
// ---------------------------------------------------------------------------
template <int ACT, int OUTBF>
__global__ __launch_bounds__(256, 2) void mfma_gemm(
    const unsigned short* __restrict__ A, const unsigned short* __restrict__ W,
    const float* __restrict__ bias1, const float* __restrict__ bias2,
    void* __restrict__ C, long long ldc, int Nreal, int K)
{
    __shared__ __align__(16) unsigned short As[128][32];
    __shared__ __align__(16) unsigned short Bs[128][32];
    const int tid = threadIdx.x;
    const int lane = tid & 63;
    const int wave = tid >> 6;
    const int wm = wave >> 1, wn = wave & 1;

    // XCD-aware bijective swizzle
    const int nwg = gridDim.x * gridDim.y;
    const int orig = blockIdx.y * gridDim.x + blockIdx.x;
    const int xcd = orig & 7, base = orig >> 3;
    const int q8 = nwg >> 3, r8 = nwg & 7;
    const int wg = (xcd < r8 ? xcd * (q8 + 1) : r8 * (q8 + 1) + (xcd - r8) * q8) + base;
    const int m0 = (wg / gridDim.x) * 128, n0 = (wg % gridDim.x) * 128;

    const int r = tid >> 2;
    const int ck = (tid & 3) * 8;

    const unsigned short* Ap = A + (long long)m0 * K;
    const unsigned short* Wp = W + (long long)n0 * K;

    f32x4 acc[4][4] = {};

    int4 ra0, ra1, rb0, rb1;
    ra0 = *reinterpret_cast<const int4*>(Ap + (long long)r * K + ck);
    ra1 = *reinterpret_cast<const int4*>(Ap + (long long)(r + 64) * K + ck);
    rb0 = *reinterpret_cast<const int4*>(Wp + (long long)r * K + ck);
    rb1 = *reinterpret_cast<const int4*>(Wp + (long long)(r + 64) * K + ck);

    for (int k0 = 0; k0 < K; k0 += 32) {
        __syncthreads();
        *reinterpret_cast<int4*>(&As[r][ck]) = ra0;
        *reinterpret_cast<int4*>(&As[r + 64][ck]) = ra1;
        *reinterpret_cast<int4*>(&Bs[r][ck]) = rb0;
        *reinterpret_cast<int4*>(&Bs[r + 64][ck]) = rb1;
        __syncthreads();
        if (k0 + 32 < K) {
            const int kn = k0 + 32 + ck;
            ra0 = *reinterpret_cast<const int4*>(Ap + (long long)r * K + kn);
            ra1 = *reinterpret_cast<const int4*>(Ap + (long long)(r + 64) * K + kn);
            rb0 = *reinterpret_cast<const int4*>(Wp + (long long)r * K + kn);
            rb1 = *reinterpret_cast<const int4*>(Wp + (long long)(r + 64) * K + kn);
        }
        const int lr = lane & 15, lk = (lane >> 4) * 8;
        bf16x8 af[4], bfr[4];
#pragma unroll
        for (int i = 0; i < 4; ++i) {
            af[i]  = *reinterpret_cast<const bf16x8*>(&As[wm * 64 + i * 16 + lr][lk]);
            bfr[i] = *reinterpret_cast<const bf16x8*>(&Bs[wn * 64 + i * 16 + lr][lk]);
        }
#pragma unroll
        for (int i = 0; i < 4; ++i)
#pragma unroll
            for (int j = 0; j < 4; ++j)
                acc[i][j] = __builtin_amdgcn_mfma_f32_16x16x32_bf16(
                    af[i], bfr[j], acc[i][j], 0, 0, 0);
    }

    // D mapping: col=lane&15, row=(lane>>4)*4+reg  [measured m89/m91]
    const int lr = lane & 15, lrow4 = (lane >> 4) * 4;
#pragma unroll
    for (int j = 0; j < 4; ++j) {
        const int col = n0 + wn * 64 + j * 16 + lr;
        if (col >= Nreal) continue;
        float bsum = 0.f;
        if (bias1) bsum += bias1[col];
        if (bias2) bsum += bias2[col];
#pragma unroll
        for (int i = 0; i < 4; ++i) {
#pragma unroll
            for (int rr = 0; rr < 4; ++rr) {
                const int row = m0 + wm * 64 + i * 16 + lrow4 + rr;
                float v = acc[i][j][rr] + bsum;
                if (ACT == 1) v = tanhf(v);
                if (ACT == 2) v = fmaxf(v, 0.f);
                if (OUTBF)
                    ((unsigned short*)C)[(long long)row * ldc + col] = f2bf(v);
                else
                    ((float*)C)[(long long)row * ldc + col] = v;
            }
        }
    }
}

static void mgemm(hipStream_t s, int act, int outbf,
                  const unsigned short* A, const unsigned short* W,
                  const float* b1, const float* b2,
                  void* C, long long ldc, int M, int Nreal, int K)
{
    dim3 grid((Nreal + 127) / 128, M / 128), blk(256);
    if (outbf) {
        switch (act) {
        case 1: mfma_gemm<1,1><<<grid, blk, 0, s>>>(A, W, b1, b2, C, ldc, Nreal, K); break;
        case 2: mfma_gemm<2,1><<<grid, blk, 0, s>>>(A, W, b1, b2, C, ldc, Nreal, K); break;
        default: mfma_gemm<0,1><<<grid, blk, 0, s>>>(A, W, b1, b2, C, ldc, Nreal, K); break;
        }
    } else {
        switch (act) {
        case 1: mfma_gemm<1,0><<<grid, blk, 0, s>>>(A, W, b1, b2, C, ldc, Nreal, K); break;
        case 2: mfma_gemm<2,0><<<grid, blk, 0, s>>>(A, W, b1, b2, C, ldc, Nreal, K); break;
        default: mfma_gemm<0,0><<<grid, blk, 0, s>>>(A, W, b1, b2, C, ldc, Nreal, K); break;
        }
    }
}

// ---------------------------------------------------------------------------
// Fused LSTM interval kernel. 64 blocks x 256 threads.
// Blocks 0..31  (grp 0): layer 0, step t = s       (active for s < 20)
// Blocks 32..63 (grp 1): layer 1, step t = s - 1   (active for s >= 1)
// Weights are gate-interleaved-permuted (col n' = 4h+g, g in {i,f,g,o}).
// Per block: 128x128 gates tile = dual-pair MFMA GEMM (K=512 each), then
// LDS round-trip + fused cell. h state bf16 double-buffered in hbuf:
//   slot pr   = layer0 h after step s-1  (read); slot pr^1 written (layer0)
//   slot 2+pr = layer1 h after step s-2  (read); slot 2+(pr^1) written
// c state fp32 in st_c (per-(b,h) owned by exactly one block).
// ---------------------------------------------------------------------------
__global__ __launch_bounds__(256, 1) void lstm_step_kernel(
    int s,
    const unsigned short* __restrict__ emb_bf,    // [b*T+t][512]
    const unsigned short* __restrict__ Wih0p, const unsigned short* __restrict__ Whh0p,
    const unsigned short* __restrict__ Wih1p, const unsigned short* __restrict__ Whh1p,
    const float* __restrict__ bp0, const float* __restrict__ bp1,
    unsigned short* __restrict__ hbuf,            // [4][B][512]
    float* __restrict__ st_h,                     // [2][B][512] (written at t==T-1)
    float* __restrict__ st_c,                     // [2][B][512]
    unsigned short* __restrict__ h_top)           // [b*T+t][512]
{
    __shared__ __align__(16) unsigned short As[128][32];
    __shared__ __align__(16) unsigned short Bs[128][32];
    __shared__ __align__(16) float gl[128][128];

    const int gid = blockIdx.x;
    const int grp = gid >> 5;
    if (grp == 0 ? (s >= T_) : (s < 1)) return;
    const int t = grp == 0 ? s : s - 1;
    const int pr = s & 1;

    const int tid = threadIdx.x;
    const int lane = tid & 63;
    const int wave = tid >> 6;
    const int wm = wave >> 1, wn = wave & 1;
    const int id = gid & 31;
    const int m0 = (id >> 4) * 128, n0 = (id & 15) * 128;
    const int r = tid >> 2, ck = (tid & 3) * 8;

    const unsigned short *A1, *A2, *W1, *W2;
    long long sA1, sA2;
    unsigned short* hout;
    const float* bp;
    float* c;
    if (grp == 0) {
        A1 = emb_bf + ((long long)m0 * T_ + t) * H_; sA1 = (long long)T_ * H_;
        A2 = hbuf + (long long)pr * BH_ + (long long)m0 * H_; sA2 = H_;
        W1 = Wih0p + (long long)n0 * H_; W2 = Whh0p + (long long)n0 * H_;
        hout = hbuf + (long long)(pr ^ 1) * BH_;
        bp = bp0; c = st_c;
    } else {
        A1 = hbuf + (long long)pr * BH_ + (long long)m0 * H_; sA1 = H_;
        A2 = hbuf + (long long)(2 + pr) * BH_ + (long long)m0 * H_; sA2 = H_;
        W1 = Wih1p + (long long)n0 * H_; W2 = Whh1p + (long long)n0 * H_;
        hout = hbuf + (long long)(2 + (pr ^ 1)) * BH_;
        bp = bp1; c = st_c + BH_;
    }

    f32x4 acc[4][4] = {};
    int4 ra0, ra1, rb0, rb1;
    ra0 = *reinterpret_cast<const int4*>(A1 + (long long)r * sA1 + ck);
    ra1 = *reinterpret_cast<const int4*>(A1 + (long long)(r + 64) * sA1 + ck);
    rb0 = *reinterpret_cast<const int4*>(W1 + (long long)r * H_ + ck);
    rb1 = *reinterpret_cast<const int4*>(W1 + (long long)(r + 64) * H_ + ck);

    for (int kk = 0; kk < 32; ++kk) {
        __syncthreads();
        *reinterpret_cast<int4*>(&As[r][ck]) = ra0;
        *reinterpret_cast<int4*>(&As[r + 64][ck]) = ra1;
        *reinterpret_cast<int4*>(&Bs[r][ck]) = rb0;
        *reinterpret_cast<int4*>(&Bs[r + 64][ck]) = rb1;
        __syncthreads();
        if (kk + 1 < 32) {
            const int p = (kk + 1) >> 4;
            const int k0 = ((kk + 1) & 15) * 32;
            const unsigned short* A = p ? A2 : A1;
            const long long sA = p ? sA2 : sA1;
            const unsigned short* W = p ? W2 : W1;
            ra0 = *reinterpret_cast<const int4*>(A + (long long)r * sA + k0 + ck);
            ra1 = *reinterpret_cast<const int4*>(A + (long long)(r + 64) * sA + k0 + ck);
            rb0 = *reinterpret_cast<const int4*>(W + (long long)r * H_ + k0 + ck);
            rb1 = *reinterpret_cast<const int4*>(W + (long long)(r + 64) * H_ + k0 + ck);
        }
        const int lr = lane & 15, lk = (lane >> 4) * 8;
        bf16x8 af[4], bfr[4];
#pragma unroll
        for (int i = 0; i < 4; ++i) {
            af[i]  = *reinterpret_cast<const bf16x8*>(&As[wm * 64 + i * 16 + lr][lk]);
            bfr[i] = *reinterpret_cast<const bf16x8*>(&Bs[wn * 64 + i * 16 + lr][lk]);
        }
#pragma unroll
        for (int i = 0; i < 4; ++i)
#pragma unroll
            for (int j = 0; j < 4; ++j)
                acc[i][j] = __builtin_amdgcn_mfma_f32_16x16x32_bf16(
                    af[i], bfr[j], acc[i][j], 0, 0, 0);
    }

    // dump gates tile to LDS, then fused cell
    const int lr = lane & 15, lrow4 = (lane >> 4) * 4;
    __syncthreads();
#pragma unroll
    for (int i = 0; i < 4; ++i)
#pragma unroll
        for (int j = 0; j < 4; ++j)
#pragma unroll
            for (int rr = 0; rr < 4; ++rr)
                gl[wm * 64 + i * 16 + lrow4 + rr][wn * 64 + j * 16 + lr] = acc[i][j][rr];
    __syncthreads();

    const int row = tid >> 1;
    const int hh0 = (tid & 1) * 16;
    const int b = m0 + row;
    for (int hh = hh0; hh < hh0 + 16; ++hh) {
        const int colh = (n0 >> 2) + hh;               // global h in [0,512)
        float4 g4 = *reinterpret_cast<const float4*>(&gl[row][4 * hh]);
        const float4 bb = *reinterpret_cast<const float4*>(&bp[4 * colh]);
        const float gi = g4.x + bb.x, gf = g4.y + bb.y;
        const float gg = g4.z + bb.z, go = g4.w + bb.w;
        const long long cidx = (long long)b * H_ + colh;
        const float i_ = 1.f / (1.f + expf(-gi));
        const float f_ = 1.f / (1.f + expf(-gf));
        const float o_ = 1.f / (1.f + expf(-go));
        const float cn = f_ * c[cidx] + i_ * tanhf(gg);
        const float hn = o_ * tanhf(cn);
        c[cidx] = cn;
        hout[cidx] = f2bf(hn);
        if (grp == 1) h_top[((long long)b * T_ + t) * H_ + colh] = f2bf(hn);
        if (t == T_ - 1) st_h[(long long)grp * BH_ + cidx] = hn;
    }
}

// ---------------------------------------------------------------------------
// Fused attention over bf16 ctx: logits -> softmax -> weighted sum (bf16 out).
// ---------------------------------------------------------------------------
__global__ __launch_bounds__(256) void attend_kernel(
    const unsigned short* __restrict__ ctx, int Lx,
    const float* __restrict__ proj,
    const float* __restrict__ wa, const float* __restrict__ ba,
    unsigned short* __restrict__ fcat, int off)
{
    __shared__ float p_lds[512];
    __shared__ float wa_lds[512];
    __shared__ float lg[96];
    const int bt = blockIdx.x;
    const int b = bt / T_;
    const int tid = threadIdx.x;

    p_lds[tid] = proj[(long long)bt * H_ + tid];
    p_lds[tid + 256] = proj[(long long)bt * H_ + tid + 256];
    wa_lds[tid] = wa[tid];
    wa_lds[tid + 256] = wa[tid + 256];
    __syncthreads();

    const int wid = tid >> 6, lane = tid & 63;
    const float bav = ba[0];
    for (int l = wid; l < Lx; l += 4) {
        const unsigned short* crow = ctx + ((long long)b * Lx + l) * H_;
        float acc = 0.f;
#pragma unroll
        for (int j = 0; j < 8; ++j) {
            const int hp = lane + 64 * j;
            acc += wa_lds[hp] * tanhf(bf2f(crow[hp]) + p_lds[hp]);
        }
        for (int o = 32; o > 0; o >>= 1) acc += __shfl_down(acc, o);
        if (lane == 0) lg[l] = acc + bav;
    }
    __syncthreads();
    if (tid == 0) {
        float m = -1e30f;
        for (int l = 0; l < Lx; ++l) m = fmaxf(m, lg[l]);
        float ssum = 0.f;
        for (int l = 0; l < Lx; ++l) { const float e = expf(lg[l] - m); lg[l] = e; ssum += e; }
        const float inv = 1.f / ssum;
        for (int l = 0; l < Lx; ++l) lg[l] *= inv;
    }
    __syncthreads();
    for (int hp = tid; hp < H_; hp += 256) {
        float acc = 0.f;
        for (int l = 0; l < Lx; ++l)
            acc += lg[l] * bf2f(ctx[((long long)b * Lx + l) * H_ + hp]);
        fcat[(long long)bt * (3 * H_) + off + hp] = f2bf(acc);
    }
}

// fusion_bf[:, 0:512] = h_top_bf (bf16 -> bf16, x8 vectorized)
__global__ __launch_bounds__(256) void copy_fusion_left(
    const unsigned short* __restrict__ h_top, unsigned short* __restrict__ fusion)
{
    const long long e0 = ((long long)blockIdx.x * 256 + threadIdx.x) * 8;  // < BT*H
    const long long rr = e0 >> 9, cpos = e0 & 511;
    *reinterpret_cast<u16x8*>(&fusion[rr * 1024 + cpos]) =
        *reinterpret_cast<const u16x8*>(&h_top[e0]);
}

// In-place log_softmax(BETA * x) per row of V_. Block per row.
__global__ __launch_bounds__(256) void log_softmax_kernel(float* __restrict__ out)
{
    __shared__ float red[4];
    __shared__ float bc[2];
    const long long base = (long long)blockIdx.x * V_;
    const int tid = threadIdx.x, lane = tid & 63, wid = tid >> 6;

    float m = -1e30f;
    for (int v = tid; v < V_; v += 256) m = fmaxf(m, out[base + v]);
    for (int o = 32; o > 0; o >>= 1) m = fmaxf(m, __shfl_down(m, o));
    if (lane == 0) red[wid] = m;
    __syncthreads();
    if (tid == 0) {
        float mm = red[0];
        for (int i = 1; i < 4; ++i) mm = fmaxf(mm, red[i]);
        bc[0] = mm;
    }
    __syncthreads();
    m = bc[0];

    float ssum = 0.f;
    for (int v = tid; v < V_; v += 256) ssum += expf(BETA_ * (out[base + v] - m));
    for (int o = 32; o > 0; o >>= 1) ssum += __shfl_down(ssum, o);
    if (lane == 0) red[wid] = ssum;
    __syncthreads();
    if (tid == 0) bc[1] = logf(red[0] + red[1] + red[2] + red[3]);
    __syncthreads();
    const float ls = bc[1];
    for (int v = tid; v < V_; v += 256)
        out[base + v] = BETA_ * (out[base + v] - m) - ls;
}

// ---------------------------------------------------------------------------
extern "C" void kernel_launch(void* const* d_in, const int* in_sizes, int n_in,
                              void* d_out_, int out_size, void* d_ws, size_t ws_size,
                              hipStream_t stream)
{
    const float* emb      = (const float*)d_in[0];
    const float* question = (const float*)d_in[1];
    const float* history  = (const float*)d_in[2];
    const float* image    = (const float*)d_in[3];
    const float* h0       = (const float*)d_in[4];
    const float* c0       = (const float*)d_in[5];
    const float* Wih      = (const float*)d_in[6];
    const float* Whh      = (const float*)d_in[7];
    const float* bih      = (const float*)d_in[8];
    const float* bhh      = (const float*)d_in[9];
    const float* Wq    = (const float*)d_in[10]; const float* bq    = (const float*)d_in[11];
    const float* Wansq = (const float*)d_in[12]; const float* bansq = (const float*)d_in[13];
    const float* waq   = (const float*)d_in[14]; const float* baq   = (const float*)d_in[15];
    const float* Wh    = (const float*)d_in[16]; const float* bh    = (const float*)d_in[17];
    const float* Wansh = (const float*)d_in[18]; const float* bansh = (const float*)d_in[19];
    const float* wah   = (const float*)d_in[20]; const float* bah   = (const float*)d_in[21];
    const float* Wi    = (const float*)d_in[22]; const float* bi    = (const float*)d_in[23];
    const float* Wansi = (const float*)d_in[24]; const float* bansi = (const float*)d_in[25];
    const float* wai   = (const float*)d_in[26]; const float* bai   = (const float*)d_in[27];
    const float* Wcat  = (const float*)d_in[28]; const float* bcat  = (const float*)d_in[29];
    const float* Wd1   = (const float*)d_in[30]; const float* bd1   = (const float*)d_in[31];
    const float* Wd2   = (const float*)d_in[32]; const float* bd2   = (const float*)d_in[33];

    float* out = (float*)d_out_;
    float* ws  = (float*)d_ws;

    // ---- workspace layout ----
    float* st_h = ws;                                  // 2*BH fp32 (then st_c: contiguous for tail copy)
    float* st_c = st_h + 2LL * BH_;                    // 2*BH fp32
    float* bp0  = st_c + 2LL * BH_;                    // 2048
    float* bp1  = bp0 + 2048;                          // 2048
    unsigned short* hbuf   = (unsigned short*)(bp1 + 2048);     // 4*BH bf16
    unsigned short* Wih0p  = hbuf + 4LL * BH_;                  // 2048*512 each
    unsigned short* Whh0p  = Wih0p + 2048LL * H_;
    unsigned short* Wih1p  = Whh0p + 2048LL * H_;
    unsigned short* Whh1p  = Wih1p + 2048LL * H_;
    unsigned short* emb_bf = Whh1p + 2048LL * H_;               // BT*H
    unsigned short* h_top_bf = emb_bf + (long long)BT_ * H_;    // BT*H
    unsigned short* q_emb_bf = h_top_bf + (long long)BT_ * H_;  // B*LQ*H
    unsigned short* h_emb_bf = q_emb_bf + (long long)B_ * LQ_ * H_;
    unsigned short* i_emb_bf = h_emb_bf + (long long)B_ * LH_ * H_;
    unsigned short* dec1_bf  = i_emb_bf + (long long)B_ * LI_ * H_;  // BT*4H
    unsigned short* Wd2p_bf  = dec1_bf + (long long)BT_ * 4 * H_;    // NPAD*4H

    // ---- phase-A scratch inside d_out (dead before phase C) ----
    unsigned short* q_bf  = (unsigned short*)out;                   // B*LQ*2H
    unsigned short* hi_bf = q_bf  + (long long)B_ * LQ_ * 2 * H_;   // B*LH*2H
    unsigned short* im_bf = hi_bf + (long long)B_ * LH_ * 2 * H_;   // B*LI*2H
    unsigned short* Wq_bf = im_bf + (long long)B_ * LI_ * 2 * H_;   // H*2H
    unsigned short* Wh_bf = Wq_bf + (long long)H_ * 2 * H_;
    unsigned short* Wi_bf = Wh_bf + (long long)H_ * 2 * H_;

    // 1) phase-A converts
    cvt(stream, question, q_bf, 1, (long long)B_ * LQ_ * 2 * H_, 1);
    cvt(stream, history,  hi_bf, 1, (long long)B_ * LH_ * 2 * H_, 1);
    cvt(stream, image,    im_bf, 1, (long long)B_ * LI_ * 2 * H_, 1);
    cvt(stream, Wq, Wq_bf, 1, (long long)H_ * 2 * H_, 1);
    cvt(stream, Wh, Wh_bf, 1, (long long)H_ * 2 * H_, 1);
    cvt(stream, Wi, Wi_bf, 1, (long long)H_ * 2 * H_, 1);

    // 2) LSTM prep: emb, permuted weights, permuted bias sums, state init
    cvt(stream, emb, emb_bf, 1, (long long)BT_ * H_, 1);
    cvt_perm_kernel<<<dim3(512), dim3(256), 0, stream>>>(Wih, Wih0p);
    cvt_perm_kernel<<<dim3(512), dim3(256), 0, stream>>>(Whh, Whh0p);
    cvt_perm_kernel<<<dim3(512), dim3(256), 0, stream>>>(Wih + 2048LL * H_, Wih1p);
    cvt_perm_kernel<<<dim3(512), dim3(256), 0, stream>>>(Whh + 2048LL * H_, Whh1p);
    bias_perm_kernel<<<dim3(8), dim3(256), 0, stream>>>(bih, bhh, bp0);
    bias_perm_kernel<<<dim3(8), dim3(256), 0, stream>>>(bih + 2048, bhh + 2048, bp1);
    cvt(stream, h0, hbuf, 1, BH_, 1);                 // layer0 init -> slot 0
    cvt(stream, h0 + BH_, hbuf + 3LL * BH_, 1, BH_, 1); // layer1 init -> slot 3
    hipMemcpyAsync(st_c, c0, 2LL * BH_ * sizeof(float), hipMemcpyDeviceToDevice, stream);

    // 3) context projections
    mgemm(stream, 0, 1, q_bf, Wq_bf, bq, nullptr, q_emb_bf, H_, B_ * LQ_, H_, 2 * H_);
    mgemm(stream, 0, 1, hi_bf, Wh_bf, bh, nullptr, h_emb_bf, H_, B_ * LH_, H_, 2 * H_);
    mgemm(stream, 0, 1, im_bf, Wi_bf, bi, nullptr, i_emb_bf, H_, B_ * LI_, H_, 2 * H_);

    // 4) fused LSTM: 21 pipelined intervals (kernel boundary = device barrier)
    for (int s = 0; s <= T_; ++s)
        lstm_step_kernel<<<dim3(64), dim3(256), 0, stream>>>(
            s, emb_bf, Wih0p, Whh0p, Wih1p, Whh1p, bp0, bp1,
            hbuf, st_h, st_c, h_top_bf);

    // ---- phase-C scratch inside d_out ----
    float* proj = out;                                              // BT*H fp32
    unsigned short* fcat_bf   = (unsigned short*)(proj + (long long)BT_ * H_); // BT*3H
    unsigned short* fusion_bf = fcat_bf + (long long)BT_ * 3 * H_;  // BT*2H
    unsigned short* Wansq_bf  = fusion_bf + (long long)BT_ * 2 * H_;
    unsigned short* Wansh_bf  = Wansq_bf + (long long)H_ * H_;
    unsigned short* Wansi_bf  = Wansh_bf + (long long)H_ * H_;
    unsigned short* Wcat_bf   = Wansi_bf + (long long)H_ * H_;      // H*3H
    unsigned short* Wd1_bf    = Wcat_bf + (long long)H_ * 3 * H_;   // 4H*2H

    // 5) phase-C converts
    cvt(stream, Wansq, Wansq_bf, 1, (long long)H_ * H_, 1);
    cvt(stream, Wansh, Wansh_bf, 1, (long long)H_ * H_, 1);
    cvt(stream, Wansi, Wansi_bf, 1, (long long)H_ * H_, 1);
    cvt(stream, Wcat, Wcat_bf, 1, (long long)H_ * 3 * H_, 1);
    cvt(stream, Wd1, Wd1_bf, 1, (long long)4 * H_ * 2 * H_, 1);
    cvt(stream, Wd2, Wd2p_bf, V_, (long long)4 * H_, NPAD_);

    // 6) attentions
    mgemm(stream, 0, 0, h_top_bf, Wansq_bf, bansq, nullptr, proj, H_, BT_, H_, H_);
    attend_kernel<<<dim3(BT_), dim3(256), 0, stream>>>(q_emb_bf, LQ_, proj, waq, baq, fcat_bf, 0);
    mgemm(stream, 0, 0, h_top_bf, Wansh_bf, bansh, nullptr, proj, H_, BT_, H_, H_);
    attend_kernel<<<dim3(BT_), dim3(256), 0, stream>>>(h_emb_bf, LH_, proj, wah, bah, fcat_bf, 512);
    mgemm(stream, 0, 0, h_top_bf, Wansi_bf, bansi, nullptr, proj, H_, BT_, H_, H_);
    attend_kernel<<<dim3(BT_), dim3(256), 0, stream>>>(i_emb_bf, LI_, proj, wai, bai, fcat_bf, 1024);

    // 7) fusion = [h_top, tanh(fcat @ Wcat^T + bcat)]
    copy_fusion_left<<<dim3(BT_ * H_ / 8 / 256), dim3(256), 0, stream>>>(h_top_bf, fusion_bf);
    mgemm(stream, 1, 1, fcat_bf, Wcat_bf, bcat, nullptr, fusion_bf + H_, 2 * H_, BT_, H_, 3 * H_);

    // 8) decoder
    mgemm(stream, 2, 1, fusion_bf, Wd1_bf, bd1, nullptr, dec1_bf, 4 * H_, BT_, 4 * H_, 2 * H_);
    mgemm(stream, 0, 0, dec1_bf, Wd2p_bf, bd2, nullptr, out, V_, BT_, V_, 4 * H_);

    // 9) in-place log_softmax(BETA * dec)
    log_softmax_kernel<<<dim3(BT_), dim3(256), 0, stream>>>(out);

    // 10) tail: hT, cT (st_h/st_c contiguous)
    hipMemcpyAsync(out + (long long)BT_ * V_, st_h,
                   4LL * BH_ * sizeof(float), hipMemcpyDeviceToDevice, stream);
}